// Round 7
// baseline (307.000 us; speedup 1.0000x reference)
//
#include <hip/hip_runtime.h>
#include <hip/hip_bf16.h>
#include <math.h>

// Problem constants (fixed by setup_inputs)
#define BB 16
#define TT 8192
#define DD 256
#define MAXSEG 4096   // max possible segments per row (alternating pattern)
#define RPB 8         // compacted segment rows per gemm block
#define CAP 32768     // compacted-segment capacity (E[total]=14336, sigma~110)
#define LN_EPS 1e-5f

typedef float vfloat4 __attribute__((ext_vector_type(4)));  // nontemporal-safe

__device__ inline float4 f4add(float4 a, float4 b) {
    a.x += b.x; a.y += b.y; a.z += b.z; a.w += b.w; return a;
}

// ---------------------------------------------------------------------------
// Setup kernel (merged): blocks [0,BB) run the per-batch-row segment scan;
// blocks [BB, BB+64) transpose W (4 rows each); block BB+64 computes
// LN(b_proj) with a single wave. 1024 threads each.
__global__ __launch_bounds__(1024) void setup_kernel(
    const int* __restrict__ ids, const float* __restrict__ W,
    const float* __restrict__ bp, const float* __restrict__ gamma,
    const float* __restrict__ beta, int* __restrict__ counts,
    int* __restrict__ seg_start, int* __restrict__ nseg_g,
    float* __restrict__ mask_out, float* __restrict__ Wt,
    float* __restrict__ ln_empty) {
    __shared__ int wtot_s[16];
    __shared__ int wtot_n[16];
    __shared__ int segs[MAXSEG];
    __shared__ int pvals[MAXSEG];

    int tid = threadIdx.x;
    int lane = tid & 63;
    int wv = tid >> 6;

    if (blockIdx.x >= BB) {
        int bi = blockIdx.x - BB;
        if (bi < 64) {  // transpose: 4 d-rows per block
            int d = bi * 4 + (tid >> 8);
            int e = tid & 255;
            Wt[d * DD + e] = W[e * DD + d];
        } else if (wv == 0) {  // LN of b_proj, one wave
            int e0 = lane * 4;
            float4 v = *(const float4*)(bp + e0);
            float s = v.x + v.y + v.z + v.w;
            float sq = v.x * v.x + v.y * v.y + v.z * v.z + v.w * v.w;
#pragma unroll
            for (int o = 32; o > 0; o >>= 1) {
                s += __shfl_down(s, o);
                sq += __shfl_down(sq, o);
            }
            s = __shfl(s, 0);
            sq = __shfl(sq, 0);
            float mu = s * (1.f / (float)DD);
            float var = sq * (1.f / (float)DD) - mu * mu;
            float rs = rsqrtf(fmaxf(var, 0.f) + LN_EPS);
            float4 ge = *(const float4*)(gamma + e0);
            float4 be = *(const float4*)(beta + e0);
            float4 o4;
            o4.x = (v.x - mu) * rs * ge.x + be.x;
            o4.y = (v.y - mu) * rs * ge.y + be.y;
            o4.z = (v.z - mu) * rs * ge.z + be.z;
            o4.w = (v.w - mu) * rs * ge.w + be.w;
            *(float4*)(ln_empty + e0) = o4;
        }
        return;
    }

    // ---- segment scan, one block per batch row
    const int TPT = 8;  // tokens per thread
    int b = blockIdx.x;
    const int* row = ids + b * TT;
    int t0 = tid * TPT;

    int4 q0 = ((const int4*)(row + t0))[0];
    int4 q1 = ((const int4*)(row + t0))[1];
    int v[TPT] = {q0.x, q0.y, q0.z, q0.w, q1.x, q1.y, q1.z, q1.w};
    int prev = (tid == 0) ? 0 : row[t0 - 1];  // 0 == boundary

    bool nb[TPT], st[TPT];
    int cstart = 0, cnon = 0;
#pragma unroll
    for (int j = 0; j < TPT; ++j) {
        nb[j] = (v[j] != 0);
        int pv = (j == 0) ? prev : v[j - 1];
        st[j] = nb[j] && (pv == 0);
        cstart += st[j] ? 1 : 0;
        cnon += nb[j] ? 1 : 0;
    }

    int ss = cstart, sn = cnon;
#pragma unroll
    for (int o = 1; o < 64; o <<= 1) {
        int us = __shfl_up(ss, o);
        int un = __shfl_up(sn, o);
        if (lane >= o) { ss += us; sn += un; }
    }
    if (lane == 63) { wtot_s[wv] = ss; wtot_n[wv] = sn; }
    __syncthreads();

    int bs = 0, bn = 0, tot_s = 0, tot_n = 0;
#pragma unroll
    for (int j = 0; j < 16; ++j) {
        int a = wtot_s[j], c = wtot_n[j];
        if (j < wv) { bs += a; bn += c; }
        tot_s += a; tot_n += c;
    }
    bs += ss - cstart;  // exclusive prefix
    bn += sn - cnon;

#pragma unroll
    for (int j = 0; j < TPT; ++j) {
        if (st[j]) { segs[bs] = t0 + j; pvals[bs] = bn; bs++; }
        bn += nb[j] ? 1 : 0;
    }
    __syncthreads();

    int ns = tot_s;
    for (int w = tid; w < TT; w += 1024) {
        int c = 0;
        if (w < ns) {
            int pe = (w + 1 < ns) ? pvals[w + 1] : tot_n;
            c = pe - pvals[w];
            seg_start[b * TT + w] = segs[w];
        }
        counts[b * TT + w] = c;
        mask_out[b * TT + w] = (w < ns) ? 1.0f : 0.0f;
    }
    if (tid == 0) nseg_g[b] = ns;
}

// ---------------------------------------------------------------------------
// Helper: build batch-offset prefix table in LDS (offs[b] = sum nseg[<b]).
__device__ inline void build_offs(const int* __restrict__ nseg, int* offs,
                                  int tid) {
    if (tid < BB) offs[tid + 1] = nseg[tid];
    if (tid == 0) offs[0] = 0;
    __syncthreads();
    if (tid == 0) {
#pragma unroll
        for (int b = 0; b < BB; ++b) offs[b + 1] += offs[b];
    }
    __syncthreads();
}

// ---------------------------------------------------------------------------
// Pool kernel: ONE WAVE per compacted segment g. 8-deep unrolled float4
// gather (max MLP), mean, dense write to pooled[g][256].
__global__ __launch_bounds__(256) void pool_kernel(
    const float* __restrict__ x, const int* __restrict__ counts,
    const int* __restrict__ seg_start, const int* __restrict__ nseg,
    float* __restrict__ pooled) {
    __shared__ int offs[BB + 1];
    int tid = threadIdx.x;
    int lane = tid & 63;
    int wv = tid >> 6;
    build_offs(nseg, offs, tid);
    int tot = offs[BB];

    int g = blockIdx.x * 4 + wv;
    if (g >= tot) return;
    int b = 0;
    while (g >= offs[b + 1]) ++b;   // wave-uniform
    int w = g - offs[b];
    int s = seg_start[b * TT + w];
    int len = counts[b * TT + w];

    const float4* xp = (const float4*)(x + ((size_t)(b * TT + s)) * DD) + lane;
    float4 a[8];
#pragma unroll
    for (int j = 0; j < 8; ++j) a[j] = make_float4(0.f, 0.f, 0.f, 0.f);
    int t = 0;
    for (; t + 8 <= len; t += 8) {
#pragma unroll
        for (int j = 0; j < 8; ++j) a[j] = f4add(a[j], xp[(t + j) * 64]);
    }
    for (; t < len; ++t) a[0] = f4add(a[0], xp[t * 64]);
    float4 r0 = f4add(f4add(a[0], a[1]), f4add(a[2], a[3]));
    float4 r1 = f4add(f4add(a[4], a[5]), f4add(a[6], a[7]));
    float4 r = f4add(r0, r1);
    float inv = 1.f / (float)len;
    r.x *= inv; r.y *= inv; r.z *= inv; r.w *= inv;
    *(float4*)(pooled + (size_t)g * DD + 4 * lane) = r;
}

// ---------------------------------------------------------------------------
// GEMM+LN over compacted rows: block owns rows [8g0, 8g0+8). Dense LDS
// staging, register-prefetched Wt column loop (thread = 1 col x 8 rows),
// cross-wave LN reduction, per-row coalesced scatter store.
__global__ __launch_bounds__(256) void gemm_ln(
    const float* __restrict__ pooled, const float* __restrict__ Wt,
    const float* __restrict__ bp, const float* __restrict__ gamma,
    const float* __restrict__ beta, const int* __restrict__ nseg,
    float* __restrict__ out) {
    __shared__ float pl[RPB][DD];   // 8 KB
    __shared__ float red[4][RPB][2];
    __shared__ int offs[BB + 1];

    int tid = threadIdx.x;
    int lane = tid & 63;
    int wv = tid >> 6;
    build_offs(nseg, offs, tid);
    int tot = offs[BB];
    int g0 = blockIdx.x * RPB;
    if (g0 >= tot) return;

    // ---- stage 8 pooled rows (coalesced global float4 -> LDS)
#pragma unroll
    for (int rr = 0; rr < 2; ++rr) {
        int r = wv * 2 + rr;
        int g = g0 + r;
        float4 v = make_float4(0.f, 0.f, 0.f, 0.f);
        if (g < tot) v = *(const float4*)(pooled + (size_t)g * DD + 4 * lane);
        *(float4*)&pl[r][lane * 4] = v;
    }
    __syncthreads();

    // ---- GEMM: acc[r] = bp[c] + sum_d pl[r][d] * Wt[d][c]
    int c = wv * 64 + lane;
    float acc[RPB];
    float bias = bp[c];
#pragma unroll
    for (int r = 0; r < RPB; ++r) acc[r] = bias;

    const float* Wc = Wt + c;
    float w0 = Wc[0 * DD];
    float w1 = Wc[1 * DD];
    float w2 = Wc[2 * DD];
    float w3 = Wc[3 * DD];
#pragma unroll 1
    for (int d0 = 0; d0 < DD; d0 += 4) {
        int dn = (d0 + 4) & 255;  // wraps harmlessly on last iter
        float n0 = Wc[(dn + 0) * DD];
        float n1 = Wc[(dn + 1) * DD];
        float n2 = Wc[(dn + 2) * DD];
        float n3 = Wc[(dn + 3) * DD];
#pragma unroll
        for (int r = 0; r < RPB; ++r) {
            const float4 p = *(const float4*)&pl[r][d0];  // wave-uniform broadcast
            acc[r] = fmaf(p.x, w0, acc[r]);
            acc[r] = fmaf(p.y, w1, acc[r]);
            acc[r] = fmaf(p.z, w2, acc[r]);
            acc[r] = fmaf(p.w, w3, acc[r]);
        }
        w0 = n0; w1 = n1; w2 = n2; w3 = n3;
    }

    // ---- LN: wave-partials over 64 cols, combined across 4 waves via LDS
#pragma unroll
    for (int r = 0; r < RPB; ++r) {
        float s = acc[r];
        float sq = acc[r] * acc[r];
#pragma unroll
        for (int o = 32; o > 0; o >>= 1) {
            s += __shfl_down(s, o);
            sq += __shfl_down(sq, o);
        }
        if (lane == 0) { red[wv][r][0] = s; red[wv][r][1] = sq; }
    }
    __syncthreads();

    float ga = gamma[c], be = beta[c];
    int b = 0;
#pragma unroll
    for (int r = 0; r < RPB; ++r) {
        int g = g0 + r;
        if (g < tot) {  // block-nonuniform only at the very last work block
            while (g >= offs[b + 1]) ++b;
            int w = g - offs[b];
            float s = red[0][r][0] + red[1][r][0] + red[2][r][0] + red[3][r][0];
            float sq = red[0][r][1] + red[1][r][1] + red[2][r][1] + red[3][r][1];
            float mu = s * (1.f / (float)DD);
            float var = sq * (1.f / (float)DD) - mu * mu;
            float rs = rsqrtf(fmaxf(var, 0.f) + LN_EPS);
            float v = (acc[r] - mu) * rs * ga + be;
            __builtin_nontemporal_store(v, out + ((size_t)(b * TT + w)) * DD + c);
        }
    }
}

// ---------------------------------------------------------------------------
// Fill kernel: tiles entirely past nseg[b] -> 8 rows of LN(b_proj).
__global__ __launch_bounds__(256) void fill_kernel(const int* __restrict__ nseg,
                                                   const float* __restrict__ ln_e,
                                                   float* __restrict__ out) {
    int b = blockIdx.x;
    int wbase = blockIdx.y * RPB;
    if (wbase < nseg[b]) return;        // work kernels cover these tiles
    int tid = threadIdx.x;
    int lane = tid & 63;
    int wv = tid >> 6;
    vfloat4 lv = *(const vfloat4*)(ln_e + 4 * lane);
    float* o = out + ((size_t)(b * TT + wbase)) * DD + 4 * lane;
#pragma unroll
    for (int rr = 0; rr < 2; ++rr) {
        int row = wv * 2 + rr;
        __builtin_nontemporal_store(lv, (vfloat4*)(o + (size_t)row * DD));
    }
}

// ---------------------------------------------------------------------------
extern "C" void kernel_launch(void* const* d_in, const int* in_sizes, int n_in,
                              void* d_out, int out_size, void* d_ws, size_t ws_size,
                              hipStream_t stream) {
    const float* x = (const float*)d_in[0];
    const int* ids = (const int*)d_in[1];
    const float* W = (const float*)d_in[2];
    const float* bp = (const float*)d_in[3];
    const float* gamma = (const float*)d_in[4];
    const float* beta = (const float*)d_in[5];

    float* out = (float*)d_out;                       // [B, T, D]
    float* mask = out + (size_t)BB * TT * DD;         // [B, T]

    // workspace layout
    char* ws = (char*)d_ws;
    int* counts = (int*)ws;                                    // B*T ints
    int* seg_start = (int*)(ws + (size_t)BB * TT * 4);         // B*T ints
    int* nseg = (int*)(ws + (size_t)2 * BB * TT * 4);          // B ints
    float* Wt = (float*)(ws + (size_t)2 * BB * TT * 4 + 256);  // D*D floats
    float* ln_e = Wt + DD * DD;                                // D floats
    float* pooled = ln_e + DD;                                 // CAP*D floats (32 MB)

    hipLaunchKernelGGL(setup_kernel, dim3(BB + 64 + 1), dim3(1024), 0, stream,
                       ids, W, bp, gamma, beta, counts, seg_start, nseg, mask,
                       Wt, ln_e);
    hipLaunchKernelGGL(pool_kernel, dim3(CAP / 4), dim3(256), 0, stream,
                       x, counts, seg_start, nseg, pooled);
    hipLaunchKernelGGL(gemm_ln, dim3(CAP / RPB), dim3(256), 0, stream,
                       pooled, Wt, bp, gamma, beta, nseg, out);
    hipLaunchKernelGGL(fill_kernel, dim3(BB, TT / RPB), dim3(256), 0, stream,
                       nseg, ln_e, out);
}

// Round 8
// 281.647 us; speedup vs baseline: 1.0900x; 1.0900x over previous
//
#include <hip/hip_runtime.h>
#include <hip/hip_bf16.h>
#include <math.h>

// Problem constants (fixed by setup_inputs)
#define BB 16
#define TT 8192
#define DD 256
#define MAXSEG 4096   // max possible segments per row (alternating pattern)
#define RPB 8         // segment rows per block
#define LN_EPS 1e-5f

typedef float vfloat4 __attribute__((ext_vector_type(4)));  // nontemporal-safe

__device__ inline float4 f4add(float4 a, float4 b) {
    a.x += b.x; a.y += b.y; a.z += b.z; a.w += b.w; return a;
}

// ---------------------------------------------------------------------------
// Setup kernel (merged): blocks [0,BB) run the per-batch-row segment scan;
// blocks [BB, BB+64) transpose W (4 rows each); block BB+64 computes
// LN(b_proj) with a single wave. 1024 threads each.
__global__ __launch_bounds__(1024) void setup_kernel(
    const int* __restrict__ ids, const float* __restrict__ W,
    const float* __restrict__ bp, const float* __restrict__ gamma,
    const float* __restrict__ beta, int* __restrict__ counts,
    int* __restrict__ seg_start, int* __restrict__ nseg_g,
    float* __restrict__ mask_out, float* __restrict__ Wt,
    float* __restrict__ ln_empty) {
    __shared__ int wtot_s[16];
    __shared__ int wtot_n[16];
    __shared__ int segs[MAXSEG];
    __shared__ int pvals[MAXSEG];

    int tid = threadIdx.x;
    int lane = tid & 63;
    int wv = tid >> 6;

    if (blockIdx.x >= BB) {
        int bi = blockIdx.x - BB;
        if (bi < 64) {  // transpose: 4 d-rows per block
            int d = bi * 4 + (tid >> 8);
            int e = tid & 255;
            Wt[d * DD + e] = W[e * DD + d];
        } else if (wv == 0) {  // LN of b_proj, one wave
            int e0 = lane * 4;
            float4 v = *(const float4*)(bp + e0);
            float s = v.x + v.y + v.z + v.w;
            float sq = v.x * v.x + v.y * v.y + v.z * v.z + v.w * v.w;
#pragma unroll
            for (int o = 32; o > 0; o >>= 1) {
                s += __shfl_down(s, o);
                sq += __shfl_down(sq, o);
            }
            s = __shfl(s, 0);
            sq = __shfl(sq, 0);
            float mu = s * (1.f / (float)DD);
            float var = sq * (1.f / (float)DD) - mu * mu;
            float rs = rsqrtf(fmaxf(var, 0.f) + LN_EPS);
            float4 ge = *(const float4*)(gamma + e0);
            float4 be = *(const float4*)(beta + e0);
            float4 o4;
            o4.x = (v.x - mu) * rs * ge.x + be.x;
            o4.y = (v.y - mu) * rs * ge.y + be.y;
            o4.z = (v.z - mu) * rs * ge.z + be.z;
            o4.w = (v.w - mu) * rs * ge.w + be.w;
            *(float4*)(ln_empty + e0) = o4;
        }
        return;
    }

    // ---- segment scan, one block per batch row
    const int TPT = 8;  // tokens per thread
    int b = blockIdx.x;
    const int* row = ids + b * TT;
    int t0 = tid * TPT;

    int4 q0 = ((const int4*)(row + t0))[0];
    int4 q1 = ((const int4*)(row + t0))[1];
    int v[TPT] = {q0.x, q0.y, q0.z, q0.w, q1.x, q1.y, q1.z, q1.w};
    int prev = (tid == 0) ? 0 : row[t0 - 1];  // 0 == boundary

    bool nb[TPT], st[TPT];
    int cstart = 0, cnon = 0;
#pragma unroll
    for (int j = 0; j < TPT; ++j) {
        nb[j] = (v[j] != 0);
        int pv = (j == 0) ? prev : v[j - 1];
        st[j] = nb[j] && (pv == 0);
        cstart += st[j] ? 1 : 0;
        cnon += nb[j] ? 1 : 0;
    }

    int ss = cstart, sn = cnon;
#pragma unroll
    for (int o = 1; o < 64; o <<= 1) {
        int us = __shfl_up(ss, o);
        int un = __shfl_up(sn, o);
        if (lane >= o) { ss += us; sn += un; }
    }
    if (lane == 63) { wtot_s[wv] = ss; wtot_n[wv] = sn; }
    __syncthreads();

    int bs = 0, bn = 0, tot_s = 0, tot_n = 0;
#pragma unroll
    for (int j = 0; j < 16; ++j) {
        int a = wtot_s[j], c = wtot_n[j];
        if (j < wv) { bs += a; bn += c; }
        tot_s += a; tot_n += c;
    }
    bs += ss - cstart;  // exclusive prefix
    bn += sn - cnon;

#pragma unroll
    for (int j = 0; j < TPT; ++j) {
        if (st[j]) { segs[bs] = t0 + j; pvals[bs] = bn; bs++; }
        bn += nb[j] ? 1 : 0;
    }
    __syncthreads();

    int ns = tot_s;
    for (int w = tid; w < TT; w += 1024) {
        int c = 0;
        if (w < ns) {
            int pe = (w + 1 < ns) ? pvals[w + 1] : tot_n;
            c = pe - pvals[w];
            seg_start[b * TT + w] = segs[w];
        }
        counts[b * TT + w] = c;
        mask_out[b * TT + w] = (w < ns) ? 1.0f : 0.0f;
    }
    if (tid == 0) nseg_g[b] = ns;
}

// ---------------------------------------------------------------------------
// Fused pool -> GEMM -> LN -> store, covering ALL tiles (fill included so the
// 117 MB of fill writes overlap the 470 MB x-read stream — both BW-bound).
// 256 threads = 4 waves. Wave wv pools rows {2wv, 2wv+1}; padding rows get
// zeros and thus compute exactly LN(b_proj). GEMM: thread owns col
// c = wv*64+lane for all 8 rows; Wt register-prefetched one d-quad ahead.
// Memory model (measured R4/R6/R7): x reads mostly hit L3 (harness restore
// keeps it hot — FETCH_SIZE ~58 MB vs 470 MB logical); stores nontemporal so
// the output doesn't evict x from L3. Roofline ~96 us for this kernel.
__global__ __launch_bounds__(256) void fused_kernel(
    const float* __restrict__ x, const float* __restrict__ Wt,
    const float* __restrict__ bp, const float* __restrict__ gamma,
    const float* __restrict__ beta, const int* __restrict__ counts,
    const int* __restrict__ seg_start, const int* __restrict__ nseg,
    const float* __restrict__ ln_e, float* __restrict__ out) {
    __shared__ float pooled[RPB][DD];   // 8 KB
    __shared__ float red[4][RPB][2];

    int b = blockIdx.x;
    int wbase = blockIdx.y * RPB;
    int ns = nseg[b];
    int tid = threadIdx.x;
    int lane = tid & 63;
    int wv = tid >> 6;
    size_t rowbase = ((size_t)(b * TT + wbase)) * DD;

    if (wbase >= ns) {  // pure fill tile: 8 rows of LN(b_proj)
        vfloat4 lv = *(const vfloat4*)(ln_e + 4 * lane);
        float* o = out + rowbase + 4 * lane;
#pragma unroll
        for (int rr = 0; rr < 2; ++rr) {
            int row = wv * 2 + rr;
            __builtin_nontemporal_store(lv, (vfloat4*)(o + (size_t)row * DD));
        }
        return;
    }
    int nr = min(RPB, ns - wbase);

    // ---- pooling: 2 rows per wave, padding rows zeroed
#pragma unroll
    for (int rr = 0; rr < 2; ++rr) {
        int row = wv * 2 + rr;
        float4 a0 = {0, 0, 0, 0};
        if (row < nr) {
            int w = wbase + row;
            int s = seg_start[b * TT + w];
            int len = counts[b * TT + w];
            const float4* xp = (const float4*)(x + ((size_t)(b * TT + s)) * DD) + lane;
            float4 a1 = a0, a2 = a0, a3 = a0;
            int t = 0;
            for (; t + 4 <= len; t += 4) {
                a0 = f4add(a0, xp[(t + 0) * 64]);
                a1 = f4add(a1, xp[(t + 1) * 64]);
                a2 = f4add(a2, xp[(t + 2) * 64]);
                a3 = f4add(a3, xp[(t + 3) * 64]);
            }
            for (; t < len; ++t) a0 = f4add(a0, xp[t * 64]);
            a0 = f4add(f4add(a0, a1), f4add(a2, a3));
            float inv = 1.f / (float)len;
            a0.x *= inv; a0.y *= inv; a0.z *= inv; a0.w *= inv;
        }
        *(float4*)&pooled[row][lane * 4] = a0;
    }
    __syncthreads();

    // ---- GEMM: acc[r] = bp[c] + sum_d pooled[r][d] * Wt[d][c]
    int c = wv * 64 + lane;
    float acc[RPB];
    float bias = bp[c];
#pragma unroll
    for (int r = 0; r < RPB; ++r) acc[r] = bias;

    const float* Wc = Wt + c;
    float w0 = Wc[0 * DD];
    float w1 = Wc[1 * DD];
    float w2 = Wc[2 * DD];
    float w3 = Wc[3 * DD];
#pragma unroll 1
    for (int d0 = 0; d0 < DD; d0 += 4) {
        int dn = (d0 + 4) & 255;  // wraps harmlessly on last iter
        float n0 = Wc[(dn + 0) * DD];
        float n1 = Wc[(dn + 1) * DD];
        float n2 = Wc[(dn + 2) * DD];
        float n3 = Wc[(dn + 3) * DD];
#pragma unroll
        for (int r = 0; r < RPB; ++r) {
            const float4 p = *(const float4*)&pooled[r][d0];  // broadcast
            acc[r] = fmaf(p.x, w0, acc[r]);
            acc[r] = fmaf(p.y, w1, acc[r]);
            acc[r] = fmaf(p.z, w2, acc[r]);
            acc[r] = fmaf(p.w, w3, acc[r]);
        }
        w0 = n0; w1 = n1; w2 = n2; w3 = n3;
    }

    // ---- LN: wave-partials over 64 cols, combined across 4 waves via LDS.
    // Padding rows (pooled==0 -> acc==bias) produce exactly LN(b_proj).
#pragma unroll
    for (int r = 0; r < RPB; ++r) {
        float s = acc[r];
        float sq = acc[r] * acc[r];
#pragma unroll
        for (int o = 32; o > 0; o >>= 1) {
            s += __shfl_down(s, o);
            sq += __shfl_down(sq, o);
        }
        if (lane == 0) { red[wv][r][0] = s; red[wv][r][1] = sq; }
    }
    __syncthreads();

    float ga = gamma[c], be = beta[c];
#pragma unroll
    for (int r = 0; r < RPB; ++r) {
        float s = red[0][r][0] + red[1][r][0] + red[2][r][0] + red[3][r][0];
        float sq = red[0][r][1] + red[1][r][1] + red[2][r][1] + red[3][r][1];
        float mu = s * (1.f / (float)DD);
        float var = sq * (1.f / (float)DD) - mu * mu;
        float rs = rsqrtf(fmaxf(var, 0.f) + LN_EPS);
        float v = (acc[r] - mu) * rs * ga + be;
        __builtin_nontemporal_store(v, out + rowbase + (size_t)r * DD + c);
    }
}

// ---------------------------------------------------------------------------
extern "C" void kernel_launch(void* const* d_in, const int* in_sizes, int n_in,
                              void* d_out, int out_size, void* d_ws, size_t ws_size,
                              hipStream_t stream) {
    const float* x = (const float*)d_in[0];
    const int* ids = (const int*)d_in[1];
    const float* W = (const float*)d_in[2];
    const float* bp = (const float*)d_in[3];
    const float* gamma = (const float*)d_in[4];
    const float* beta = (const float*)d_in[5];

    float* out = (float*)d_out;                       // [B, T, D]
    float* mask = out + (size_t)BB * TT * DD;         // [B, T]

    // workspace layout
    char* ws = (char*)d_ws;
    int* counts = (int*)ws;                                    // B*T ints
    int* seg_start = (int*)(ws + (size_t)BB * TT * 4);         // B*T ints
    int* nseg = (int*)(ws + (size_t)2 * BB * TT * 4);          // B ints
    float* Wt = (float*)(ws + (size_t)2 * BB * TT * 4 + 256);  // D*D floats
    float* ln_e = Wt + DD * DD;                                // D floats

    hipLaunchKernelGGL(setup_kernel, dim3(BB + 64 + 1), dim3(1024), 0, stream,
                       ids, W, bp, gamma, beta, counts, seg_start, nseg, mask,
                       Wt, ln_e);
    hipLaunchKernelGGL(fused_kernel, dim3(BB, TT / RPB), dim3(256), 0, stream,
                       x, Wt, bp, gamma, beta, counts, seg_start, nseg, ln_e, out);
}

// Round 9
// 270.945 us; speedup vs baseline: 1.1331x; 1.0395x over previous
//
#include <hip/hip_runtime.h>
#include <hip/hip_bf16.h>
#include <math.h>

// Problem constants (fixed by setup_inputs)
#define BB 16
#define TT 8192
#define DD 256
#define MAXSEG 4096   // max possible segments per row (alternating pattern)
#define RPB 8         // segment rows per block
#define LN_EPS 1e-5f

typedef float vfloat4 __attribute__((ext_vector_type(4)));  // nontemporal-safe

// ---------------------------------------------------------------------------
// Setup kernel (merged): blocks [0,BB) run the per-batch-row segment scan;
// blocks [BB, BB+64) transpose W (4 rows each); block BB+64 computes
// LN(b_proj) with a single wave. 1024 threads each.
__global__ __launch_bounds__(1024) void setup_kernel(
    const int* __restrict__ ids, const float* __restrict__ W,
    const float* __restrict__ bp, const float* __restrict__ gamma,
    const float* __restrict__ beta, int* __restrict__ counts,
    int* __restrict__ seg_start, int* __restrict__ nseg_g,
    float* __restrict__ mask_out, float* __restrict__ Wt,
    float* __restrict__ ln_empty) {
    __shared__ int wtot_s[16];
    __shared__ int wtot_n[16];
    __shared__ int segs[MAXSEG];
    __shared__ int pvals[MAXSEG];

    int tid = threadIdx.x;
    int lane = tid & 63;
    int wv = tid >> 6;

    if (blockIdx.x >= BB) {
        int bi = blockIdx.x - BB;
        if (bi < 64) {  // transpose: 4 d-rows per block
            int d = bi * 4 + (tid >> 8);
            int e = tid & 255;
            Wt[d * DD + e] = W[e * DD + d];
        } else if (wv == 0) {  // LN of b_proj, one wave
            int e0 = lane * 4;
            float4 v = *(const float4*)(bp + e0);
            float s = v.x + v.y + v.z + v.w;
            float sq = v.x * v.x + v.y * v.y + v.z * v.z + v.w * v.w;
#pragma unroll
            for (int o = 32; o > 0; o >>= 1) {
                s += __shfl_down(s, o);
                sq += __shfl_down(sq, o);
            }
            s = __shfl(s, 0);
            sq = __shfl(sq, 0);
            float mu = s * (1.f / (float)DD);
            float var = sq * (1.f / (float)DD) - mu * mu;
            float rs = rsqrtf(fmaxf(var, 0.f) + LN_EPS);
            float4 ge = *(const float4*)(gamma + e0);
            float4 be = *(const float4*)(beta + e0);
            float4 o4;
            o4.x = (v.x - mu) * rs * ge.x + be.x;
            o4.y = (v.y - mu) * rs * ge.y + be.y;
            o4.z = (v.z - mu) * rs * ge.z + be.z;
            o4.w = (v.w - mu) * rs * ge.w + be.w;
            *(float4*)(ln_empty + e0) = o4;
        }
        return;
    }

    // ---- segment scan, one block per batch row
    const int TPT = 8;  // tokens per thread
    int b = blockIdx.x;
    const int* row = ids + b * TT;
    int t0 = tid * TPT;

    int4 q0 = ((const int4*)(row + t0))[0];
    int4 q1 = ((const int4*)(row + t0))[1];
    int v[TPT] = {q0.x, q0.y, q0.z, q0.w, q1.x, q1.y, q1.z, q1.w};
    int prev = (tid == 0) ? 0 : row[t0 - 1];  // 0 == boundary

    bool nb[TPT], st[TPT];
    int cstart = 0, cnon = 0;
#pragma unroll
    for (int j = 0; j < TPT; ++j) {
        nb[j] = (v[j] != 0);
        int pv = (j == 0) ? prev : v[j - 1];
        st[j] = nb[j] && (pv == 0);
        cstart += st[j] ? 1 : 0;
        cnon += nb[j] ? 1 : 0;
    }

    int ss = cstart, sn = cnon;
#pragma unroll
    for (int o = 1; o < 64; o <<= 1) {
        int us = __shfl_up(ss, o);
        int un = __shfl_up(sn, o);
        if (lane >= o) { ss += us; sn += un; }
    }
    if (lane == 63) { wtot_s[wv] = ss; wtot_n[wv] = sn; }
    __syncthreads();

    int bs = 0, bn = 0, tot_s = 0, tot_n = 0;
#pragma unroll
    for (int j = 0; j < 16; ++j) {
        int a = wtot_s[j], c = wtot_n[j];
        if (j < wv) { bs += a; bn += c; }
        tot_s += a; tot_n += c;
    }
    bs += ss - cstart;  // exclusive prefix
    bn += sn - cnon;

#pragma unroll
    for (int j = 0; j < TPT; ++j) {
        if (st[j]) { segs[bs] = t0 + j; pvals[bs] = bn; bs++; }
        bn += nb[j] ? 1 : 0;
    }
    __syncthreads();

    int ns = tot_s;
    for (int w = tid; w < TT; w += 1024) {
        int c = 0;
        if (w < ns) {
            int pe = (w + 1 < ns) ? pvals[w + 1] : tot_n;
            c = pe - pvals[w];
            seg_start[b * TT + w] = segs[w];
        }
        counts[b * TT + w] = c;
        mask_out[b * TT + w] = (w < ns) ? 1.0f : 0.0f;
    }
    if (tid == 0) nseg_g[b] = ns;
}

// ---------------------------------------------------------------------------
// Fused pool -> GEMM -> LN -> store, covering ALL tiles.
// Pooling uses 8 independent accumulators + a fully-predicated 7-load tail so
// short segments (mean len ~7, geometric) never serialize loads back-to-back.
// x loads nontemporal (single-use; keep L2 clean, L3 hits still hit).
__global__ __launch_bounds__(256) void fused_kernel(
    const float* __restrict__ x, const float* __restrict__ Wt,
    const float* __restrict__ bp, const float* __restrict__ gamma,
    const float* __restrict__ beta, const int* __restrict__ counts,
    const int* __restrict__ seg_start, const int* __restrict__ nseg,
    const float* __restrict__ ln_e, float* __restrict__ out) {
    __shared__ float pooled[RPB][DD];   // 8 KB
    __shared__ float red[4][RPB][2];

    int b = blockIdx.x;
    int wbase = blockIdx.y * RPB;
    int ns = nseg[b];
    int tid = threadIdx.x;
    int lane = tid & 63;
    int wv = tid >> 6;
    size_t rowbase = ((size_t)(b * TT + wbase)) * DD;

    if (wbase >= ns) {  // pure fill tile: 8 rows of LN(b_proj)
        vfloat4 lv = *(const vfloat4*)(ln_e + 4 * lane);
        float* o = out + rowbase + 4 * lane;
#pragma unroll
        for (int rr = 0; rr < 2; ++rr) {
            int row = wv * 2 + rr;
            __builtin_nontemporal_store(lv, (vfloat4*)(o + (size_t)row * DD));
        }
        return;
    }
    int nr = min(RPB, ns - wbase);

    // ---- pooling: 2 rows per wave; all loads independent (8 accumulators)
#pragma unroll
    for (int rr = 0; rr < 2; ++rr) {
        int row = wv * 2 + rr;
        vfloat4 r = {0.f, 0.f, 0.f, 0.f};
        if (row < nr) {
            int w = wbase + row;
            int s = seg_start[b * TT + w];
            int len = counts[b * TT + w];
            const vfloat4* xp =
                (const vfloat4*)(x + ((size_t)(b * TT + s)) * DD) + lane;
            vfloat4 a[8];
#pragma unroll
            for (int j = 0; j < 8; ++j) a[j] = (vfloat4){0.f, 0.f, 0.f, 0.f};
            int t = 0;
            for (; t + 8 <= len; t += 8) {
#pragma unroll
                for (int j = 0; j < 8; ++j)
                    a[j] += __builtin_nontemporal_load(xp + (t + j) * 64);
            }
            // tail: up to 7 loads, wave-uniform predicates, independent accs
#pragma unroll
            for (int j = 0; j < 7; ++j)
                if (t + j < len)
                    a[j] += __builtin_nontemporal_load(xp + (t + j) * 64);
            r = ((a[0] + a[1]) + (a[2] + a[3])) + ((a[4] + a[5]) + (a[6] + a[7]));
            r *= (1.f / (float)len);
        }
        *(vfloat4*)&pooled[row][lane * 4] = r;
    }
    __syncthreads();

    // ---- GEMM: acc[r] = bp[c] + sum_d pooled[r][d] * Wt[d][c]
    int c = wv * 64 + lane;
    float acc[RPB];
    float bias = bp[c];
#pragma unroll
    for (int r = 0; r < RPB; ++r) acc[r] = bias;

    const float* Wc = Wt + c;
    float w0 = Wc[0 * DD];
    float w1 = Wc[1 * DD];
    float w2 = Wc[2 * DD];
    float w3 = Wc[3 * DD];
#pragma unroll 1
    for (int d0 = 0; d0 < DD; d0 += 4) {
        int dn = (d0 + 4) & 255;  // wraps harmlessly on last iter
        float n0 = Wc[(dn + 0) * DD];
        float n1 = Wc[(dn + 1) * DD];
        float n2 = Wc[(dn + 2) * DD];
        float n3 = Wc[(dn + 3) * DD];
#pragma unroll
        for (int r = 0; r < RPB; ++r) {
            const float4 p = *(const float4*)&pooled[r][d0];  // broadcast
            acc[r] = fmaf(p.x, w0, acc[r]);
            acc[r] = fmaf(p.y, w1, acc[r]);
            acc[r] = fmaf(p.z, w2, acc[r]);
            acc[r] = fmaf(p.w, w3, acc[r]);
        }
        w0 = n0; w1 = n1; w2 = n2; w3 = n3;
    }

    // ---- LN: wave-partials over 64 cols, combined across 4 waves via LDS.
    // Padding rows (pooled==0 -> acc==bias) produce exactly LN(b_proj).
#pragma unroll
    for (int r = 0; r < RPB; ++r) {
        float s = acc[r];
        float sq = acc[r] * acc[r];
#pragma unroll
        for (int o = 32; o > 0; o >>= 1) {
            s += __shfl_down(s, o);
            sq += __shfl_down(sq, o);
        }
        if (lane == 0) { red[wv][r][0] = s; red[wv][r][1] = sq; }
    }
    __syncthreads();

    float ga = gamma[c], be = beta[c];
#pragma unroll
    for (int r = 0; r < RPB; ++r) {
        float s = red[0][r][0] + red[1][r][0] + red[2][r][0] + red[3][r][0];
        float sq = red[0][r][1] + red[1][r][1] + red[2][r][1] + red[3][r][1];
        float mu = s * (1.f / (float)DD);
        float var = sq * (1.f / (float)DD) - mu * mu;
        float rs = rsqrtf(fmaxf(var, 0.f) + LN_EPS);
        float v = (acc[r] - mu) * rs * ga + be;
        __builtin_nontemporal_store(v, out + rowbase + (size_t)r * DD + c);
    }
}

// ---------------------------------------------------------------------------
extern "C" void kernel_launch(void* const* d_in, const int* in_sizes, int n_in,
                              void* d_out, int out_size, void* d_ws, size_t ws_size,
                              hipStream_t stream) {
    const float* x = (const float*)d_in[0];
    const int* ids = (const int*)d_in[1];
    const float* W = (const float*)d_in[2];
    const float* bp = (const float*)d_in[3];
    const float* gamma = (const float*)d_in[4];
    const float* beta = (const float*)d_in[5];

    float* out = (float*)d_out;                       // [B, T, D]
    float* mask = out + (size_t)BB * TT * DD;         // [B, T]

    // workspace layout
    char* ws = (char*)d_ws;
    int* counts = (int*)ws;                                    // B*T ints
    int* seg_start = (int*)(ws + (size_t)BB * TT * 4);         // B*T ints
    int* nseg = (int*)(ws + (size_t)2 * BB * TT * 4);          // B ints
    float* Wt = (float*)(ws + (size_t)2 * BB * TT * 4 + 256);  // D*D floats
    float* ln_e = Wt + DD * DD;                                // D floats

    hipLaunchKernelGGL(setup_kernel, dim3(BB + 64 + 1), dim3(1024), 0, stream,
                       ids, W, bp, gamma, beta, counts, seg_start, nseg, mask,
                       Wt, ln_e);
    hipLaunchKernelGGL(fused_kernel, dim3(BB, TT / RPB), dim3(256), 0, stream,
                       x, Wt, bp, gamma, beta, counts, seg_start, nseg, ln_e, out);
}